// Round 1
// baseline (5446.440 us; speedup 1.0000x reference)
//
#include <hip/hip_runtime.h>

typedef float floatx4 __attribute__((ext_vector_type(4)));
typedef long longx2 __attribute__((ext_vector_type(2)));
typedef unsigned int u32;
typedef unsigned char u8;

#define MDIM 4096
#define HDIM 4096
#define IDIM 14336
#define FP8MAX 448.0f

// ---------------------------------------------------------------------------
// LDS tile geometry (BK=64): 128 rows x 64 B per buffer (8 KB).
// 16B chunk c of row r lives at slot (c ^ swz4(r)), swz4(r) = (r^(r>>2))&3.
// -> b128 column-slice reads spread evenly over all bank groups (floor-rate).
// global_load_lds writes LINEARLY (uniform base + lane*16), so we pre-swizzle
// the per-lane GLOBAL source address instead (both-sides-or-neither rule).
// ---------------------------------------------------------------------------
__device__ __forceinline__ int swz4(int r) { return (r ^ (r >> 2)) & 3; }
__device__ __forceinline__ int frag_off(int row, int quad) {
  return (row << 6) + ((quad ^ swz4(row)) << 4);
}

__device__ __forceinline__ void gload16(const u8* g, u8* l) {
  __builtin_amdgcn_global_load_lds((const __attribute__((address_space(1))) u32*)g,
                                   (__attribute__((address_space(3))) u32*)l, 16, 0, 0);
}

// ---------------------------------------------------------------------------
// Weight-dtype detection: 2 = fp32, 1 = bf16, 0 = raw fp8 bytes.
// ---------------------------------------------------------------------------
__global__ void detect_dtype(const unsigned int* __restrict__ w, int* __restrict__ flag) {
  if (threadIdx.x == 0 && blockIdx.x == 0) {
    bool f32 = true, b16 = true;
    for (int i = 0; i < 64; ++i) {
      const unsigned int v = w[i];
      if (v & 0xFFFFFu) f32 = false;
      if ((v & 0xFu) || ((v >> 16) & 0xFu)) b16 = false;
    }
    *flag = f32 ? 2 : (b16 ? 1 : 0);
  }
}

__device__ __forceinline__ float bfu(unsigned int bits16) {
  union { unsigned int u; float f; } c;
  c.u = bits16 << 16;
  return c.f;
}

__device__ __forceinline__ unsigned int pack2(unsigned int lo, unsigned int hi) {
  int pk = __builtin_amdgcn_cvt_pk_fp8_f32(bfu(lo & 0xFFFFu), bfu(lo >> 16), 0, false);
  pk = __builtin_amdgcn_cvt_pk_fp8_f32(bfu(hi & 0xFFFFu), bfu(hi >> 16), pk, true);
  return (unsigned int)pk;
}

// Convert one weight matrix to fp8 bytes. flag==0 (already fp8): no-op, the
// GEMMs read the raw input buffer directly.
__global__ __launch_bounds__(256) void conv_w(const void* __restrict__ src,
                                              unsigned char* __restrict__ dst,
                                              const int* __restrict__ flag_p) {
  const int flag = *flag_p;
  if (flag == 0) return;
  const long t = (long)blockIdx.x * 256 + threadIdx.x;  // 16 elements per thread
  uint4 out;
  if (flag == 2) {
    const float4* s = (const float4*)src;
    unsigned int o[4];
#pragma unroll
    for (int p = 0; p < 4; ++p) {
      const float4 v = s[t * 4 + p];
      int pk = __builtin_amdgcn_cvt_pk_fp8_f32(v.x, v.y, 0, false);
      pk = __builtin_amdgcn_cvt_pk_fp8_f32(v.z, v.w, pk, true);
      o[p] = (unsigned int)pk;
    }
    out = make_uint4(o[0], o[1], o[2], o[3]);
  } else {
    const uint4* s = (const uint4*)src;
    const uint4 a = s[t * 2], b = s[t * 2 + 1];
    out = make_uint4(pack2(a.x, a.y), pack2(a.z, a.w),
                     pack2(b.x, b.y), pack2(b.z, b.w));
  }
  ((uint4*)dst)[t] = out;
}

// ---------------------------------------------------------------------------
// Kernel 1: fake-quant activations. One wave per (row, 128-col group).
// ---------------------------------------------------------------------------
__global__ __launch_bounds__(256) void fq_act(const float* __restrict__ x,
                                              unsigned char* __restrict__ xq,
                                              float* __restrict__ xsT) {
  const int tid = threadIdx.x;
  const int lane = tid & 63, w = tid >> 6;
  const int g = blockIdx.x * 4 + w;
  const int row = g >> 5, kb = g & 31;

  const float2 v = ((const float2*)(x + (size_t)row * HDIM + kb * 128))[lane];
  float amax = fmaxf(fabsf(v.x), fabsf(v.y));
#pragma unroll
  for (int off = 1; off < 64; off <<= 1)
    amax = fmaxf(amax, __shfl_xor(amax, off, 64));

  const float scale = fmaxf(amax / FP8MAX, 1e-12f);
  const float q0 = fminf(fmaxf(v.x / scale, -FP8MAX), FP8MAX);
  const float q1 = fminf(fmaxf(v.y / scale, -FP8MAX), FP8MAX);
  const int pk = __builtin_amdgcn_cvt_pk_fp8_f32(q0, q1, 0, false);
  ((unsigned short*)(xq + (size_t)row * HDIM + kb * 128))[lane] = (unsigned short)(pk & 0xFFFF);
  if (lane == 0) xsT[(size_t)kb * MDIM + row] = scale;
}

// ---------------------------------------------------------------------------
// Kernel 2: fused gate/up blockwise-fp8 GEMM + silu*u + per-row-128 fake quant.
// BK=64 double-buffered 2-phase pipeline, global_load_lds staging.
// ---------------------------------------------------------------------------
__global__ __launch_bounds__(256, 2)
void dual_gemm_silu_fq(const u8* __restrict__ xq, const float* __restrict__ xsT,
                       const u8* __restrict__ gw_cv, const u8* __restrict__ gw_raw,
                       const float* __restrict__ gs,
                       const u8* __restrict__ uw_cv, const u8* __restrict__ uw_raw,
                       const float* __restrict__ us,
                       u8* __restrict__ hq, float* __restrict__ hsT,
                       const int* __restrict__ flag_p, const int use_conv) {
  // [A|G|U] x [buf0|buf1] x 8 KB
  __shared__ __align__(16) u8 lds[49152];

  const int tid = threadIdx.x;
  const int lane = tid & 63, wid = tid >> 6;
  const int quad = lane >> 4, l16 = lane & 15;

  // XCD-chunked swizzle: 3584 = 8 * 448 (bijective). Keeps the 32 blocks that
  // share one weight strip (mi-inner) on a single XCD's L2.
  const int bid0 = blockIdx.x;
  const int bid = (bid0 & 7) * 448 + (bid0 >> 3);
  const int mi = bid & 31, ni = bid >> 5;
  const size_t m0 = (size_t)mi << 7, n0 = (size_t)ni << 7;

  const u8* gw = gw_raw;
  const u8* uw = uw_raw;
  if (use_conv) {
    if (*flag_p != 0) { gw = gw_cv; uw = uw_cv; }
  }

  const u8* baseA = xq + m0 * HDIM;
  const u8* baseG = gw + n0 * HDIM;
  const u8* baseU = uw + n0 * HDIM;

  // staging: per wave 2 issues per tile, 16 rows (1 KB linear) per issue;
  // source pre-swizzled so swizzled chunks land at linear LDS offsets.
  const int r16 = lane >> 2, slot = lane & 3;
  u32 srcoff[2], dstoff[2];
#pragma unroll
  for (int i = 0; i < 2; ++i) {
    const int row = wid * 32 + i * 16 + r16;
    srcoff[i] = (u32)(row * HDIM) + (u32)((slot ^ swz4(row)) << 4);
    dstoff[i] = (u32)(wid * 2048 + i * 1024);
  }

  // fragment read offsets within one 8 KB buffer (K map: k8 = quad*2 + j)
  int offA[2], offB[8];
#pragma unroll
  for (int mt = 0; mt < 2; ++mt) offA[mt] = frag_off(wid * 32 + mt * 16 + l16, quad);
#pragma unroll
  for (int nt = 0; nt < 8; ++nt) offB[nt] = frag_off(nt * 16 + l16, quad);

  floatx4 accG[2][8], accU[2][8];
#pragma unroll
  for (int mt = 0; mt < 2; ++mt)
#pragma unroll
    for (int nt = 0; nt < 8; ++nt) {
      accG[mt][nt] = {0.f, 0.f, 0.f, 0.f};
      accU[mt][nt] = {0.f, 0.f, 0.f, 0.f};
    }

  auto STAGE = [&](int t, int b) {
    const u32 ko = (u32)t << 6;
    const u32 bo = (u32)b << 13;
#pragma unroll
    for (int i = 0; i < 2; ++i) {
      gload16(baseA + srcoff[i] + ko, &lds[bo + dstoff[i]]);
      gload16(baseG + srcoff[i] + ko, &lds[16384u + bo + dstoff[i]]);
      gload16(baseU + srcoff[i] + ko, &lds[32768u + bo + dstoff[i]]);
    }
  };

  float xsv[2][4], sg, su;

  auto HALF = [&](int b) {
    const u8* bufA = lds + (b << 13);
    const u8* bufG = lds + 16384 + (b << 13);
    const u8* bufU = lds + 32768 + (b << 13);
    longx2 aF[2];
#pragma unroll
    for (int mt = 0; mt < 2; ++mt) aF[mt] = *(const longx2*)(bufA + offA[mt]);

    floatx4 blk[2][8];
    // ---- gate ----
#pragma unroll
    for (int mt = 0; mt < 2; ++mt)
#pragma unroll
      for (int nt = 0; nt < 8; ++nt) blk[mt][nt] = {0.f, 0.f, 0.f, 0.f};
    __builtin_amdgcn_s_setprio(1);
#pragma unroll
    for (int nt = 0; nt < 8; ++nt) {
      const longx2 bF = *(const longx2*)(bufG + offB[nt]);
#pragma unroll
      for (int mt = 0; mt < 2; ++mt) {
        blk[mt][nt] = __builtin_amdgcn_mfma_f32_16x16x32_fp8_fp8(aF[mt][0], bF[0], blk[mt][nt], 0, 0, 0);
        blk[mt][nt] = __builtin_amdgcn_mfma_f32_16x16x32_fp8_fp8(aF[mt][1], bF[1], blk[mt][nt], 0, 0, 0);
      }
    }
    __builtin_amdgcn_s_setprio(0);
#pragma unroll
    for (int mt = 0; mt < 2; ++mt) {
      float pr[4];
#pragma unroll
      for (int r = 0; r < 4; ++r) pr[r] = xsv[mt][r] * sg;
#pragma unroll
      for (int nt = 0; nt < 8; ++nt)
#pragma unroll
        for (int r = 0; r < 4; ++r) accG[mt][nt][r] += blk[mt][nt][r] * pr[r];
    }
    // ---- up (reuses aF) ----
#pragma unroll
    for (int mt = 0; mt < 2; ++mt)
#pragma unroll
      for (int nt = 0; nt < 8; ++nt) blk[mt][nt] = {0.f, 0.f, 0.f, 0.f};
    __builtin_amdgcn_s_setprio(1);
#pragma unroll
    for (int nt = 0; nt < 8; ++nt) {
      const longx2 bF = *(const longx2*)(bufU + offB[nt]);
#pragma unroll
      for (int mt = 0; mt < 2; ++mt) {
        blk[mt][nt] = __builtin_amdgcn_mfma_f32_16x16x32_fp8_fp8(aF[mt][0], bF[0], blk[mt][nt], 0, 0, 0);
        blk[mt][nt] = __builtin_amdgcn_mfma_f32_16x16x32_fp8_fp8(aF[mt][1], bF[1], blk[mt][nt], 0, 0, 0);
      }
    }
    __builtin_amdgcn_s_setprio(0);
#pragma unroll
    for (int mt = 0; mt < 2; ++mt) {
      float pr[4];
#pragma unroll
      for (int r = 0; r < 4; ++r) pr[r] = xsv[mt][r] * su;
#pragma unroll
      for (int nt = 0; nt < 8; ++nt)
#pragma unroll
        for (int r = 0; r < 4; ++r) accU[mt][nt][r] += blk[mt][nt][r] * pr[r];
    }
  };

  STAGE(0, 0);
  asm volatile("s_waitcnt vmcnt(0)" ::: "memory");
  __builtin_amdgcn_s_barrier();

  for (int kb = 0; kb < 32; ++kb) {
    sg = gs[ni * 32 + kb];
    su = us[ni * 32 + kb];
#pragma unroll
    for (int mt = 0; mt < 2; ++mt) {
      const float4 v = *(const float4*)(xsT + (size_t)kb * MDIM + m0 + wid * 32 + mt * 16 + quad * 4);
      xsv[mt][0] = v.x; xsv[mt][1] = v.y; xsv[mt][2] = v.z; xsv[mt][3] = v.w;
    }
    STAGE(2 * kb + 1, 1);          // prefetch odd half under even-half compute
    HALF(0);
    asm volatile("s_waitcnt vmcnt(0)" ::: "memory");
    __builtin_amdgcn_s_barrier();
    if (kb + 1 < 32) STAGE(2 * kb + 2, 0);
    HALF(1);
    asm volatile("s_waitcnt vmcnt(0)" ::: "memory");
    __builtin_amdgcn_s_barrier();
  }

  // ---- epilogue: h = silu(g)*u, per-row fake quant over this 128-col group --
#pragma unroll
  for (int mt = 0; mt < 2; ++mt) {
    float h[8][4];
    float amax[4] = {0.f, 0.f, 0.f, 0.f};
#pragma unroll
    for (int nt = 0; nt < 8; ++nt)
#pragma unroll
      for (int r = 0; r < 4; ++r) {
        const float gv = accG[mt][nt][r];
        const float uv = accU[mt][nt][r];
        const float hv = (gv / (1.f + __expf(-gv))) * uv;
        h[nt][r] = hv;
        amax[r] = fmaxf(amax[r], fabsf(hv));
      }
#pragma unroll
    for (int off = 1; off < 16; off <<= 1)
#pragma unroll
      for (int r = 0; r < 4; ++r)
        amax[r] = fmaxf(amax[r], __shfl_xor(amax[r], off, 64));

    float scale[4];
#pragma unroll
    for (int r = 0; r < 4; ++r) scale[r] = fmaxf(amax[r] / FP8MAX, 1e-12f);

    const int rowl = wid * 32 + mt * 16 + quad * 4;
    if (l16 == 0) {
#pragma unroll
      for (int r = 0; r < 4; ++r)
        hsT[(size_t)ni * MDIM + m0 + rowl + r] = scale[r];
    }
#pragma unroll
    for (int nt = 0; nt < 8; ++nt)
#pragma unroll
      for (int r = 0; r < 4; ++r) {
        const float q = fminf(fmaxf(h[nt][r] / scale[r], -FP8MAX), FP8MAX);
        const int pk = __builtin_amdgcn_cvt_pk_fp8_f32(q, 0.f, 0, false);
        hq[(m0 + rowl + r) * (size_t)IDIM + n0 + nt * 16 + l16] = (u8)(pk & 0xFF);
      }
  }
}

// ---------------------------------------------------------------------------
// Kernel 3: down projection. Same pipeline; blk persists across both halves
// of a 128-K block (fold once per kb -> half the fold VALU of the dual GEMM).
// ---------------------------------------------------------------------------
__global__ __launch_bounds__(256, 2)
void gemm_down(const u8* __restrict__ hq, const float* __restrict__ hsT,
               const u8* __restrict__ dw_cv, const u8* __restrict__ dw_raw,
               const float* __restrict__ dsc, float* __restrict__ out,
               const int* __restrict__ flag_p, const int use_conv) {
  __shared__ __align__(16) u8 lds[32768];  // [A|B] x [buf0|buf1] x 8 KB

  const int tid = threadIdx.x;
  const int lane = tid & 63, wid = tid >> 6;
  const int quad = lane >> 4, l16 = lane & 15;

  const int bid0 = blockIdx.x;
  const int bid = (bid0 & 7) * 128 + (bid0 >> 3);  // 1024 = 8 * 128
  const int mi = bid & 31, ni = bid >> 5;
  const size_t m0 = (size_t)mi << 7, n0 = (size_t)ni << 7;

  const u8* dw = dw_raw;
  if (use_conv) {
    if (*flag_p != 0) dw = dw_cv;
  }

  const u8* baseA = hq + m0 * IDIM;
  const u8* baseB = dw + n0 * IDIM;

  const int r16 = lane >> 2, slot = lane & 3;
  u32 srcoff[2], dstoff[2];
#pragma unroll
  for (int i = 0; i < 2; ++i) {
    const int row = wid * 32 + i * 16 + r16;
    srcoff[i] = (u32)(row * IDIM) + (u32)((slot ^ swz4(row)) << 4);
    dstoff[i] = (u32)(wid * 2048 + i * 1024);
  }

  int offA[2], offB[8];
#pragma unroll
  for (int mt = 0; mt < 2; ++mt) offA[mt] = frag_off(wid * 32 + mt * 16 + l16, quad);
#pragma unroll
  for (int nt = 0; nt < 8; ++nt) offB[nt] = frag_off(nt * 16 + l16, quad);

  floatx4 acc[2][8], blk[2][8];
#pragma unroll
  for (int mt = 0; mt < 2; ++mt)
#pragma unroll
    for (int nt = 0; nt < 8; ++nt) acc[mt][nt] = {0.f, 0.f, 0.f, 0.f};

  auto STAGE = [&](int t, int b) {
    const u32 ko = (u32)t << 6;
    const u32 bo = (u32)b << 13;
#pragma unroll
    for (int i = 0; i < 2; ++i) {
      gload16(baseA + srcoff[i] + ko, &lds[bo + dstoff[i]]);
      gload16(baseB + srcoff[i] + ko, &lds[16384u + bo + dstoff[i]]);
    }
  };

  auto HALF = [&](int b) {
    const u8* bufA = lds + (b << 13);
    const u8* bufB = lds + 16384 + (b << 13);
    longx2 aF[2];
#pragma unroll
    for (int mt = 0; mt < 2; ++mt) aF[mt] = *(const longx2*)(bufA + offA[mt]);
    __builtin_amdgcn_s_setprio(1);
#pragma unroll
    for (int nt = 0; nt < 8; ++nt) {
      const longx2 bF = *(const longx2*)(bufB + offB[nt]);
#pragma unroll
      for (int mt = 0; mt < 2; ++mt) {
        blk[mt][nt] = __builtin_amdgcn_mfma_f32_16x16x32_fp8_fp8(aF[mt][0], bF[0], blk[mt][nt], 0, 0, 0);
        blk[mt][nt] = __builtin_amdgcn_mfma_f32_16x16x32_fp8_fp8(aF[mt][1], bF[1], blk[mt][nt], 0, 0, 0);
      }
    }
    __builtin_amdgcn_s_setprio(0);
  };

  STAGE(0, 0);
  asm volatile("s_waitcnt vmcnt(0)" ::: "memory");
  __builtin_amdgcn_s_barrier();

  float hv[2][4];
  for (int kb = 0; kb < 112; ++kb) {
    const float sd = dsc[ni * 112 + kb];
#pragma unroll
    for (int mt = 0; mt < 2; ++mt) {
      const float4 v = *(const float4*)(hsT + (size_t)kb * MDIM + m0 + wid * 32 + mt * 16 + quad * 4);
      hv[mt][0] = v.x * sd; hv[mt][1] = v.y * sd; hv[mt][2] = v.z * sd; hv[mt][3] = v.w * sd;
    }
#pragma unroll
    for (int mt = 0; mt < 2; ++mt)
#pragma unroll
      for (int nt = 0; nt < 8; ++nt) blk[mt][nt] = {0.f, 0.f, 0.f, 0.f};

    STAGE(2 * kb + 1, 1);
    HALF(0);
    asm volatile("s_waitcnt vmcnt(0)" ::: "memory");
    __builtin_amdgcn_s_barrier();
    if (kb + 1 < 112) STAGE(2 * kb + 2, 0);
    HALF(1);
#pragma unroll
    for (int mt = 0; mt < 2; ++mt)
#pragma unroll
      for (int nt = 0; nt < 8; ++nt)
#pragma unroll
        for (int r = 0; r < 4; ++r) acc[mt][nt][r] += blk[mt][nt][r] * hv[mt][r];
    asm volatile("s_waitcnt vmcnt(0)" ::: "memory");
    __builtin_amdgcn_s_barrier();
  }

#pragma unroll
  for (int mt = 0; mt < 2; ++mt) {
    const int rowl = wid * 32 + mt * 16 + quad * 4;
#pragma unroll
    for (int nt = 0; nt < 8; ++nt)
#pragma unroll
      for (int r = 0; r < 4; ++r)
        out[(m0 + rowl + r) * (size_t)HDIM + n0 + nt * 16 + l16] = acc[mt][nt][r];
  }
}

// ---------------------------------------------------------------------------
extern "C" void kernel_launch(void* const* d_in, const int* in_sizes, int n_in,
                              void* d_out, int out_size, void* d_ws, size_t ws_size,
                              hipStream_t stream) {
  const float* x   = (const float*)d_in[0];
  const void* gw_s = d_in[1];
  const float* gs  = (const float*)d_in[2];
  const void* uw_s = d_in[3];
  const float* us  = (const float*)d_in[4];
  const void* dw_s = d_in[5];
  const float* dsc = (const float*)d_in[6];
  float* out       = (float*)d_out;

  const size_t NW = (size_t)IDIM * HDIM;  // 58,720,256 elements per weight

  unsigned char* ws = (unsigned char*)d_ws;
  unsigned char* xq = ws;                         // 16 MB
  float* xsT = (float*)(ws + 16777216);           // 512 KB
  unsigned char* hq  = ws + 17301504;             // 56 MB
  float* hsT = (float*)(ws + 76021760);           // 1.75 MB
  unsigned char* gwq = ws + 77856768;             // 56 MB
  unsigned char* uwq = ws + 136577024;            // 56 MB
  unsigned char* dwq = gwq;                       // reuse gate slot after dual_gemm
  int* flag = (int*)(ws + 195297280);

  const bool fits = ws_size >= (size_t)195297284;
  const int use_conv = fits ? 1 : 0;

  const int convBlocks = (int)(NW / (16 * 256));  // 14336, exact

  if (fits) {
    detect_dtype<<<1, 64, 0, stream>>>((const unsigned int*)gw_s, flag);
    conv_w<<<convBlocks, 256, 0, stream>>>(gw_s, gwq, flag);
    conv_w<<<convBlocks, 256, 0, stream>>>(uw_s, uwq, flag);
  }
  fq_act<<<(MDIM * (HDIM / 128)) / 4, 256, 0, stream>>>(x, xq, xsT);
  dual_gemm_silu_fq<<<(MDIM / 128) * (IDIM / 128), 256, 0, stream>>>(
      xq, xsT, gwq, (const unsigned char*)gw_s, gs,
      uwq, (const unsigned char*)uw_s, us, hq, hsT, flag, use_conv);
  if (fits) {
    conv_w<<<convBlocks, 256, 0, stream>>>(dw_s, dwq, flag);
  }
  gemm_down<<<(MDIM / 128) * (HDIM / 128), 256, 0, stream>>>(
      hq, hsT, dwq, (const unsigned char*)dw_s, dsc, out, flag, use_conv);
}

// Round 2
// 5440.728 us; speedup vs baseline: 1.0010x; 1.0010x over previous
//
#include <hip/hip_runtime.h>

typedef float floatx4 __attribute__((ext_vector_type(4)));
typedef long longx2 __attribute__((ext_vector_type(2)));
typedef unsigned int u32;
typedef unsigned char u8;

#define MDIM 4096
#define HDIM 4096
#define IDIM 14336
#define FP8MAX 448.0f

// ---------------------------------------------------------------------------
// LDS tile geometry (BK=64): 128 rows x 64 B per buffer (8 KB).
// 16B chunk c of row r lives at slot (c ^ swz4(r)), swz4(r) = (r^(r>>2))&3.
// global_load_lds writes LINEARLY (uniform base + lane*16), so we pre-swizzle
// the per-lane GLOBAL source address instead (both-sides-or-neither rule).
// ---------------------------------------------------------------------------
__device__ __forceinline__ int swz4(int r) { return (r ^ (r >> 2)) & 3; }
__device__ __forceinline__ int frag_off(int row, int quad) {
  return (row << 6) + ((quad ^ swz4(row)) << 4);
}

__device__ __forceinline__ void gload16(const u8* g, u8* l) {
  __builtin_amdgcn_global_load_lds((const __attribute__((address_space(1))) u32*)g,
                                   (__attribute__((address_space(3))) u32*)l, 16, 0, 0);
}

// ---------------------------------------------------------------------------
// Weight-dtype detection: 2 = fp32, 1 = bf16, 0 = raw fp8 bytes.
// ---------------------------------------------------------------------------
__global__ void detect_dtype(const unsigned int* __restrict__ w, int* __restrict__ flag) {
  if (threadIdx.x == 0 && blockIdx.x == 0) {
    bool f32 = true, b16 = true;
    for (int i = 0; i < 64; ++i) {
      const unsigned int v = w[i];
      if (v & 0xFFFFFu) f32 = false;
      if ((v & 0xFu) || ((v >> 16) & 0xFu)) b16 = false;
    }
    *flag = f32 ? 2 : (b16 ? 1 : 0);
  }
}

__device__ __forceinline__ float bfu(unsigned int bits16) {
  union { unsigned int u; float f; } c;
  c.u = bits16 << 16;
  return c.f;
}

__device__ __forceinline__ unsigned int pack2(unsigned int lo, unsigned int hi) {
  int pk = __builtin_amdgcn_cvt_pk_fp8_f32(bfu(lo & 0xFFFFu), bfu(lo >> 16), 0, false);
  pk = __builtin_amdgcn_cvt_pk_fp8_f32(bfu(hi & 0xFFFFu), bfu(hi >> 16), pk, true);
  return (unsigned int)pk;
}

// Convert one weight matrix to fp8 bytes. flag==0 (already fp8): no-op, the
// GEMMs read the raw input buffer directly.
__global__ __launch_bounds__(256) void conv_w(const void* __restrict__ src,
                                              unsigned char* __restrict__ dst,
                                              const int* __restrict__ flag_p) {
  const int flag = *flag_p;
  if (flag == 0) return;
  const long t = (long)blockIdx.x * 256 + threadIdx.x;  // 16 elements per thread
  uint4 out;
  if (flag == 2) {
    const float4* s = (const float4*)src;
    unsigned int o[4];
#pragma unroll
    for (int p = 0; p < 4; ++p) {
      const float4 v = s[t * 4 + p];
      int pk = __builtin_amdgcn_cvt_pk_fp8_f32(v.x, v.y, 0, false);
      pk = __builtin_amdgcn_cvt_pk_fp8_f32(v.z, v.w, pk, true);
      o[p] = (unsigned int)pk;
    }
    out = make_uint4(o[0], o[1], o[2], o[3]);
  } else {
    const uint4* s = (const uint4*)src;
    const uint4 a = s[t * 2], b = s[t * 2 + 1];
    out = make_uint4(pack2(a.x, a.y), pack2(a.z, a.w),
                     pack2(b.x, b.y), pack2(b.z, b.w));
  }
  ((uint4*)dst)[t] = out;
}

// ---------------------------------------------------------------------------
// Kernel 1: fake-quant activations. One wave per (row, 128-col group).
// ---------------------------------------------------------------------------
__global__ __launch_bounds__(256) void fq_act(const float* __restrict__ x,
                                              unsigned char* __restrict__ xq,
                                              float* __restrict__ xsT) {
  const int tid = threadIdx.x;
  const int lane = tid & 63, w = tid >> 6;
  const int g = blockIdx.x * 4 + w;
  const int row = g >> 5, kb = g & 31;

  const float2 v = ((const float2*)(x + (size_t)row * HDIM + kb * 128))[lane];
  float amax = fmaxf(fabsf(v.x), fabsf(v.y));
#pragma unroll
  for (int off = 1; off < 64; off <<= 1)
    amax = fmaxf(amax, __shfl_xor(amax, off, 64));

  const float scale = fmaxf(amax / FP8MAX, 1e-12f);
  const float q0 = fminf(fmaxf(v.x / scale, -FP8MAX), FP8MAX);
  const float q1 = fminf(fmaxf(v.y / scale, -FP8MAX), FP8MAX);
  const int pk = __builtin_amdgcn_cvt_pk_fp8_f32(q0, q1, 0, false);
  ((unsigned short*)(xq + (size_t)row * HDIM + kb * 128))[lane] = (unsigned short)(pk & 0xFFFF);
  if (lane == 0) xsT[(size_t)kb * MDIM + row] = scale;
}

// ---------------------------------------------------------------------------
// Kernel 2: fused gate/up blockwise-fp8 GEMM + silu*u + per-row-128 fake quant.
// BK=64 double-buffered 2-phase pipeline, global_load_lds staging.
// Epilogue: transpose hq tile through LDS -> coalesced 16B/lane stores
// (byte-scatter stores were 10.3 GB of HBM write + RMW fetch; full-line
//  writes eliminate that and stop thrashing the Infinity Cache).
// ---------------------------------------------------------------------------
__global__ __launch_bounds__(256, 2)
void dual_gemm_silu_fq(const u8* __restrict__ xq, const float* __restrict__ xsT,
                       const u8* __restrict__ gw_cv, const u8* __restrict__ gw_raw,
                       const float* __restrict__ gs,
                       const u8* __restrict__ uw_cv, const u8* __restrict__ uw_raw,
                       const float* __restrict__ us,
                       u8* __restrict__ hq, float* __restrict__ hsT,
                       const int* __restrict__ flag_p, const int use_conv) {
  // [A|G|U] x [buf0|buf1] x 8 KB; first 16 KB reused as output byte tile.
  __shared__ __align__(16) u8 lds[49152];

  const int tid = threadIdx.x;
  const int lane = tid & 63, wid = tid >> 6;
  const int quad = lane >> 4, l16 = lane & 15;

  // XCD-chunked swizzle: 3584 = 8 * 448 (bijective).
  const int bid0 = blockIdx.x;
  const int bid = (bid0 & 7) * 448 + (bid0 >> 3);
  const int mi = bid & 31, ni = bid >> 5;
  const size_t m0 = (size_t)mi << 7, n0 = (size_t)ni << 7;

  const u8* gw = gw_raw;
  const u8* uw = uw_raw;
  if (use_conv) {
    if (*flag_p != 0) { gw = gw_cv; uw = uw_cv; }
  }

  const u8* baseA = xq + m0 * HDIM;
  const u8* baseG = gw + n0 * HDIM;
  const u8* baseU = uw + n0 * HDIM;

  const int r16 = lane >> 2, slot = lane & 3;
  u32 srcoff[2], dstoff[2];
#pragma unroll
  for (int i = 0; i < 2; ++i) {
    const int row = wid * 32 + i * 16 + r16;
    srcoff[i] = (u32)(row * HDIM) + (u32)((slot ^ swz4(row)) << 4);
    dstoff[i] = (u32)(wid * 2048 + i * 1024);
  }

  int offA[2], offB[8];
#pragma unroll
  for (int mt = 0; mt < 2; ++mt) offA[mt] = frag_off(wid * 32 + mt * 16 + l16, quad);
#pragma unroll
  for (int nt = 0; nt < 8; ++nt) offB[nt] = frag_off(nt * 16 + l16, quad);

  floatx4 accG[2][8], accU[2][8];
#pragma unroll
  for (int mt = 0; mt < 2; ++mt)
#pragma unroll
    for (int nt = 0; nt < 8; ++nt) {
      accG[mt][nt] = {0.f, 0.f, 0.f, 0.f};
      accU[mt][nt] = {0.f, 0.f, 0.f, 0.f};
    }

  auto STAGE = [&](int t, int b) {
    const u32 ko = (u32)t << 6;
    const u32 bo = (u32)b << 13;
#pragma unroll
    for (int i = 0; i < 2; ++i) {
      gload16(baseA + srcoff[i] + ko, &lds[bo + dstoff[i]]);
      gload16(baseG + srcoff[i] + ko, &lds[16384u + bo + dstoff[i]]);
      gload16(baseU + srcoff[i] + ko, &lds[32768u + bo + dstoff[i]]);
    }
  };

  float xsv[2][4], sg, su;

  auto HALF = [&](int b) {
    const u8* bufA = lds + (b << 13);
    const u8* bufG = lds + 16384 + (b << 13);
    const u8* bufU = lds + 32768 + (b << 13);
    longx2 aF[2];
#pragma unroll
    for (int mt = 0; mt < 2; ++mt) aF[mt] = *(const longx2*)(bufA + offA[mt]);

    floatx4 blk[2][8];
    // ---- gate ----
#pragma unroll
    for (int mt = 0; mt < 2; ++mt)
#pragma unroll
      for (int nt = 0; nt < 8; ++nt) blk[mt][nt] = {0.f, 0.f, 0.f, 0.f};
    __builtin_amdgcn_s_setprio(1);
#pragma unroll
    for (int nt = 0; nt < 8; ++nt) {
      const longx2 bF = *(const longx2*)(bufG + offB[nt]);
#pragma unroll
      for (int mt = 0; mt < 2; ++mt) {
        blk[mt][nt] = __builtin_amdgcn_mfma_f32_16x16x32_fp8_fp8(aF[mt][0], bF[0], blk[mt][nt], 0, 0, 0);
        blk[mt][nt] = __builtin_amdgcn_mfma_f32_16x16x32_fp8_fp8(aF[mt][1], bF[1], blk[mt][nt], 0, 0, 0);
      }
    }
    __builtin_amdgcn_s_setprio(0);
#pragma unroll
    for (int mt = 0; mt < 2; ++mt) {
      float pr[4];
#pragma unroll
      for (int r = 0; r < 4; ++r) pr[r] = xsv[mt][r] * sg;
#pragma unroll
      for (int nt = 0; nt < 8; ++nt)
#pragma unroll
        for (int r = 0; r < 4; ++r) accG[mt][nt][r] += blk[mt][nt][r] * pr[r];
    }
    // ---- up (reuses aF) ----
#pragma unroll
    for (int mt = 0; mt < 2; ++mt)
#pragma unroll
      for (int nt = 0; nt < 8; ++nt) blk[mt][nt] = {0.f, 0.f, 0.f, 0.f};
    __builtin_amdgcn_s_setprio(1);
#pragma unroll
    for (int nt = 0; nt < 8; ++nt) {
      const longx2 bF = *(const longx2*)(bufU + offB[nt]);
#pragma unroll
      for (int mt = 0; mt < 2; ++mt) {
        blk[mt][nt] = __builtin_amdgcn_mfma_f32_16x16x32_fp8_fp8(aF[mt][0], bF[0], blk[mt][nt], 0, 0, 0);
        blk[mt][nt] = __builtin_amdgcn_mfma_f32_16x16x32_fp8_fp8(aF[mt][1], bF[1], blk[mt][nt], 0, 0, 0);
      }
    }
    __builtin_amdgcn_s_setprio(0);
#pragma unroll
    for (int mt = 0; mt < 2; ++mt) {
      float pr[4];
#pragma unroll
      for (int r = 0; r < 4; ++r) pr[r] = xsv[mt][r] * su;
#pragma unroll
      for (int nt = 0; nt < 8; ++nt)
#pragma unroll
        for (int r = 0; r < 4; ++r) accU[mt][nt][r] += blk[mt][nt][r] * pr[r];
    }
  };

  STAGE(0, 0);
  asm volatile("s_waitcnt vmcnt(0)" ::: "memory");
  __builtin_amdgcn_s_barrier();

  for (int kb = 0; kb < 32; ++kb) {
    sg = gs[ni * 32 + kb];
    su = us[ni * 32 + kb];
#pragma unroll
    for (int mt = 0; mt < 2; ++mt) {
      const float4 v = *(const float4*)(xsT + (size_t)kb * MDIM + m0 + wid * 32 + mt * 16 + quad * 4);
      xsv[mt][0] = v.x; xsv[mt][1] = v.y; xsv[mt][2] = v.z; xsv[mt][3] = v.w;
    }
    STAGE(2 * kb + 1, 1);          // prefetch odd half under even-half compute
    HALF(0);
    asm volatile("s_waitcnt vmcnt(0)" ::: "memory");
    __builtin_amdgcn_s_barrier();
    if (kb + 1 < 32) STAGE(2 * kb + 2, 0);
    HALF(1);
    asm volatile("s_waitcnt vmcnt(0)" ::: "memory");
    __builtin_amdgcn_s_barrier();
  }

  // ---- epilogue: h = silu(g)*u, per-row fake quant over this 128-col group.
  // Stage bytes into LDS (row-major [128][128]) then store coalesced.
  u8* ot = lds;  // 16 KB, safe: all waves past final barrier
#pragma unroll
  for (int mt = 0; mt < 2; ++mt) {
    float h[8][4];
    float amax[4] = {0.f, 0.f, 0.f, 0.f};
#pragma unroll
    for (int nt = 0; nt < 8; ++nt)
#pragma unroll
      for (int r = 0; r < 4; ++r) {
        const float gv = accG[mt][nt][r];
        const float uv = accU[mt][nt][r];
        const float hv = (gv / (1.f + __expf(-gv))) * uv;
        h[nt][r] = hv;
        amax[r] = fmaxf(amax[r], fabsf(hv));
      }
#pragma unroll
    for (int off = 1; off < 16; off <<= 1)
#pragma unroll
      for (int r = 0; r < 4; ++r)
        amax[r] = fmaxf(amax[r], __shfl_xor(amax[r], off, 64));

    float scale[4];
#pragma unroll
    for (int r = 0; r < 4; ++r) scale[r] = fmaxf(amax[r] / FP8MAX, 1e-12f);

    const int rowl = wid * 32 + mt * 16 + quad * 4;
    if (l16 == 0) {
#pragma unroll
      for (int r = 0; r < 4; ++r)
        hsT[(size_t)ni * MDIM + m0 + rowl + r] = scale[r];
    }
#pragma unroll
    for (int nt = 0; nt < 8; ++nt)
#pragma unroll
      for (int r = 0; r < 4; ++r) {
        const float q = fminf(fmaxf(h[nt][r] / scale[r], -FP8MAX), FP8MAX);
        const int pk = __builtin_amdgcn_cvt_pk_fp8_f32(q, 0.f, 0, false);
        ot[(rowl + r) * 128 + nt * 16 + l16] = (u8)(pk & 0xFF);
      }
  }
  __syncthreads();
  {
    const int row = tid >> 1, half = tid & 1;
    const uint4* s = (const uint4*)(ot + row * 128 + half * 64);
    uint4* d = (uint4*)(hq + (m0 + row) * IDIM + n0 + half * 64);
#pragma unroll
    for (int i = 0; i < 4; ++i) d[i] = s[i];
  }
}

// ---------------------------------------------------------------------------
// Kernel 3: down projection. Same pipeline; blk persists across both halves
// of a 128-K block (fold once per kb).
// ---------------------------------------------------------------------------
__global__ __launch_bounds__(256, 2)
void gemm_down(const u8* __restrict__ hq, const float* __restrict__ hsT,
               const u8* __restrict__ dw_cv, const u8* __restrict__ dw_raw,
               const float* __restrict__ dsc, float* __restrict__ out,
               const int* __restrict__ flag_p, const int use_conv) {
  __shared__ __align__(16) u8 lds[32768];  // [A|B] x [buf0|buf1] x 8 KB

  const int tid = threadIdx.x;
  const int lane = tid & 63, wid = tid >> 6;
  const int quad = lane >> 4, l16 = lane & 15;

  const int bid0 = blockIdx.x;
  const int bid = (bid0 & 7) * 128 + (bid0 >> 3);  // 1024 = 8 * 128
  const int mi = bid & 31, ni = bid >> 5;
  const size_t m0 = (size_t)mi << 7, n0 = (size_t)ni << 7;

  const u8* dw = dw_raw;
  if (use_conv) {
    if (*flag_p != 0) dw = dw_cv;
  }

  const u8* baseA = hq + m0 * IDIM;
  const u8* baseB = dw + n0 * IDIM;

  const int r16 = lane >> 2, slot = lane & 3;
  u32 srcoff[2], dstoff[2];
#pragma unroll
  for (int i = 0; i < 2; ++i) {
    const int row = wid * 32 + i * 16 + r16;
    srcoff[i] = (u32)(row * IDIM) + (u32)((slot ^ swz4(row)) << 4);
    dstoff[i] = (u32)(wid * 2048 + i * 1024);
  }

  int offA[2], offB[8];
#pragma unroll
  for (int mt = 0; mt < 2; ++mt) offA[mt] = frag_off(wid * 32 + mt * 16 + l16, quad);
#pragma unroll
  for (int nt = 0; nt < 8; ++nt) offB[nt] = frag_off(nt * 16 + l16, quad);

  floatx4 acc[2][8], blk[2][8];
#pragma unroll
  for (int mt = 0; mt < 2; ++mt)
#pragma unroll
    for (int nt = 0; nt < 8; ++nt) acc[mt][nt] = {0.f, 0.f, 0.f, 0.f};

  auto STAGE = [&](int t, int b) {
    const u32 ko = (u32)t << 6;
    const u32 bo = (u32)b << 13;
#pragma unroll
    for (int i = 0; i < 2; ++i) {
      gload16(baseA + srcoff[i] + ko, &lds[bo + dstoff[i]]);
      gload16(baseB + srcoff[i] + ko, &lds[16384u + bo + dstoff[i]]);
    }
  };

  auto HALF = [&](int b) {
    const u8* bufA = lds + (b << 13);
    const u8* bufB = lds + 16384 + (b << 13);
    longx2 aF[2];
#pragma unroll
    for (int mt = 0; mt < 2; ++mt) aF[mt] = *(const longx2*)(bufA + offA[mt]);
    __builtin_amdgcn_s_setprio(1);
#pragma unroll
    for (int nt = 0; nt < 8; ++nt) {
      const longx2 bF = *(const longx2*)(bufB + offB[nt]);
#pragma unroll
      for (int mt = 0; mt < 2; ++mt) {
        blk[mt][nt] = __builtin_amdgcn_mfma_f32_16x16x32_fp8_fp8(aF[mt][0], bF[0], blk[mt][nt], 0, 0, 0);
        blk[mt][nt] = __builtin_amdgcn_mfma_f32_16x16x32_fp8_fp8(aF[mt][1], bF[1], blk[mt][nt], 0, 0, 0);
      }
    }
    __builtin_amdgcn_s_setprio(0);
  };

  STAGE(0, 0);
  asm volatile("s_waitcnt vmcnt(0)" ::: "memory");
  __builtin_amdgcn_s_barrier();

  float hv[2][4];
  for (int kb = 0; kb < 112; ++kb) {
    const float sd = dsc[ni * 112 + kb];
#pragma unroll
    for (int mt = 0; mt < 2; ++mt) {
      const float4 v = *(const float4*)(hsT + (size_t)kb * MDIM + m0 + wid * 32 + mt * 16 + quad * 4);
      hv[mt][0] = v.x * sd; hv[mt][1] = v.y * sd; hv[mt][2] = v.z * sd; hv[mt][3] = v.w * sd;
    }
#pragma unroll
    for (int mt = 0; mt < 2; ++mt)
#pragma unroll
      for (int nt = 0; nt < 8; ++nt) blk[mt][nt] = {0.f, 0.f, 0.f, 0.f};

    STAGE(2 * kb + 1, 1);
    HALF(0);
    asm volatile("s_waitcnt vmcnt(0)" ::: "memory");
    __builtin_amdgcn_s_barrier();
    if (kb + 1 < 112) STAGE(2 * kb + 2, 0);
    HALF(1);
#pragma unroll
    for (int mt = 0; mt < 2; ++mt)
#pragma unroll
      for (int nt = 0; nt < 8; ++nt)
#pragma unroll
        for (int r = 0; r < 4; ++r) acc[mt][nt][r] += blk[mt][nt][r] * hv[mt][r];
    asm volatile("s_waitcnt vmcnt(0)" ::: "memory");
    __builtin_amdgcn_s_barrier();
  }

#pragma unroll
  for (int mt = 0; mt < 2; ++mt) {
    const int rowl = wid * 32 + mt * 16 + quad * 4;
#pragma unroll
    for (int nt = 0; nt < 8; ++nt)
#pragma unroll
      for (int r = 0; r < 4; ++r)
        out[(m0 + rowl + r) * (size_t)HDIM + n0 + nt * 16 + l16] = acc[mt][nt][r];
  }
}

// ---------------------------------------------------------------------------
extern "C" void kernel_launch(void* const* d_in, const int* in_sizes, int n_in,
                              void* d_out, int out_size, void* d_ws, size_t ws_size,
                              hipStream_t stream) {
  const float* x   = (const float*)d_in[0];
  const void* gw_s = d_in[1];
  const float* gs  = (const float*)d_in[2];
  const void* uw_s = d_in[3];
  const float* us  = (const float*)d_in[4];
  const void* dw_s = d_in[5];
  const float* dsc = (const float*)d_in[6];
  float* out       = (float*)d_out;

  const size_t NW = (size_t)IDIM * HDIM;  // 58,720,256 elements per weight

  unsigned char* ws = (unsigned char*)d_ws;
  unsigned char* xq = ws;                         // 16 MB
  float* xsT = (float*)(ws + 16777216);           // 512 KB
  unsigned char* hq  = ws + 17301504;             // 56 MB
  float* hsT = (float*)(ws + 76021760);           // 1.75 MB
  unsigned char* gwq = ws + 77856768;             // 56 MB
  unsigned char* uwq = ws + 136577024;            // 56 MB
  unsigned char* dwq = gwq;                       // reuse gate slot after dual_gemm
  int* flag = (int*)(ws + 195297280);

  const bool fits = ws_size >= (size_t)195297284;
  const int use_conv = fits ? 1 : 0;

  const int convBlocks = (int)(NW / (16 * 256));  // 14336, exact

  if (fits) {
    detect_dtype<<<1, 64, 0, stream>>>((const unsigned int*)gw_s, flag);
    conv_w<<<convBlocks, 256, 0, stream>>>(gw_s, gwq, flag);
    conv_w<<<convBlocks, 256, 0, stream>>>(uw_s, uwq, flag);
  }
  fq_act<<<(MDIM * (HDIM / 128)) / 4, 256, 0, stream>>>(x, xq, xsT);
  dual_gemm_silu_fq<<<(MDIM / 128) * (IDIM / 128), 256, 0, stream>>>(
      xq, xsT, gwq, (const unsigned char*)gw_s, gs,
      uwq, (const unsigned char*)uw_s, us, hq, hsT, flag, use_conv);
  if (fits) {
    conv_w<<<convBlocks, 256, 0, stream>>>(dw_s, dwq, flag);
  }
  gemm_down<<<(MDIM / 128) * (HDIM / 128), 256, 0, stream>>>(
      hq, hsT, dwq, (const unsigned char*)dw_s, dsc, out, flag, use_conv);
}

// Round 3
// 1982.833 us; speedup vs baseline: 2.7468x; 2.7439x over previous
//
#include <hip/hip_runtime.h>

typedef float floatx4 __attribute__((ext_vector_type(4)));
typedef long longx2 __attribute__((ext_vector_type(2)));
typedef unsigned int u32;
typedef unsigned char u8;

#define MDIM 4096
#define HDIM 4096
#define IDIM 14336
#define FP8MAX 448.0f

// ---------------------------------------------------------------------------
// LDS tile geometry (BK=64): 128 rows x 64 B per buffer (8 KB).
// 16B chunk c of row r lives at slot (c ^ swz4(r)), swz4(r) = (r^(r>>2))&3.
// global_load_lds writes LINEARLY (uniform base + lane*16), so we pre-swizzle
// the per-lane GLOBAL source address instead (both-sides-or-neither rule).
// ---------------------------------------------------------------------------
__device__ __forceinline__ int swz4(int r) { return (r ^ (r >> 2)) & 3; }
__device__ __forceinline__ int frag_off(int row, int quad) {
  return (row << 6) + ((quad ^ swz4(row)) << 4);
}

__device__ __forceinline__ void gload16(const u8* g, u8* l) {
  __builtin_amdgcn_global_load_lds((const __attribute__((address_space(1))) u32*)g,
                                   (__attribute__((address_space(3))) u32*)l, 16, 0, 0);
}

// ---------------------------------------------------------------------------
// Weight-dtype detection: 2 = fp32, 1 = bf16, 0 = raw fp8 bytes.
// ---------------------------------------------------------------------------
__global__ void detect_dtype(const unsigned int* __restrict__ w, int* __restrict__ flag) {
  if (threadIdx.x == 0 && blockIdx.x == 0) {
    bool f32 = true, b16 = true;
    for (int i = 0; i < 64; ++i) {
      const unsigned int v = w[i];
      if (v & 0xFFFFFu) f32 = false;
      if ((v & 0xFu) || ((v >> 16) & 0xFu)) b16 = false;
    }
    *flag = f32 ? 2 : (b16 ? 1 : 0);
  }
}

__device__ __forceinline__ float bfu(unsigned int bits16) {
  union { unsigned int u; float f; } c;
  c.u = bits16 << 16;
  return c.f;
}

__device__ __forceinline__ unsigned int pack2(unsigned int lo, unsigned int hi) {
  int pk = __builtin_amdgcn_cvt_pk_fp8_f32(bfu(lo & 0xFFFFu), bfu(lo >> 16), 0, false);
  pk = __builtin_amdgcn_cvt_pk_fp8_f32(bfu(hi & 0xFFFFu), bfu(hi >> 16), pk, true);
  return (unsigned int)pk;
}

// Convert one weight matrix to fp8 bytes. flag==0 (already fp8): no-op, the
// GEMMs read the raw input buffer directly.
__global__ __launch_bounds__(256) void conv_w(const void* __restrict__ src,
                                              unsigned char* __restrict__ dst,
                                              const int* __restrict__ flag_p) {
  const int flag = *flag_p;
  if (flag == 0) return;
  const long t = (long)blockIdx.x * 256 + threadIdx.x;  // 16 elements per thread
  uint4 out;
  if (flag == 2) {
    const float4* s = (const float4*)src;
    unsigned int o[4];
#pragma unroll
    for (int p = 0; p < 4; ++p) {
      const float4 v = s[t * 4 + p];
      int pk = __builtin_amdgcn_cvt_pk_fp8_f32(v.x, v.y, 0, false);
      pk = __builtin_amdgcn_cvt_pk_fp8_f32(v.z, v.w, pk, true);
      o[p] = (unsigned int)pk;
    }
    out = make_uint4(o[0], o[1], o[2], o[3]);
  } else {
    const uint4* s = (const uint4*)src;
    const uint4 a = s[t * 2], b = s[t * 2 + 1];
    out = make_uint4(pack2(a.x, a.y), pack2(a.z, a.w),
                     pack2(b.x, b.y), pack2(b.z, b.w));
  }
  ((uint4*)dst)[t] = out;
}

// ---------------------------------------------------------------------------
// Kernel 1: fake-quant activations. One wave per (row, 128-col group).
// ---------------------------------------------------------------------------
__global__ __launch_bounds__(256) void fq_act(const float* __restrict__ x,
                                              unsigned char* __restrict__ xq,
                                              float* __restrict__ xsT) {
  const int tid = threadIdx.x;
  const int lane = tid & 63, w = tid >> 6;
  const int g = blockIdx.x * 4 + w;
  const int row = g >> 5, kb = g & 31;

  const float2 v = ((const float2*)(x + (size_t)row * HDIM + kb * 128))[lane];
  float amax = fmaxf(fabsf(v.x), fabsf(v.y));
#pragma unroll
  for (int off = 1; off < 64; off <<= 1)
    amax = fmaxf(amax, __shfl_xor(amax, off, 64));

  const float scale = fmaxf(amax / FP8MAX, 1e-12f);
  const float q0 = fminf(fmaxf(v.x / scale, -FP8MAX), FP8MAX);
  const float q1 = fminf(fmaxf(v.y / scale, -FP8MAX), FP8MAX);
  const int pk = __builtin_amdgcn_cvt_pk_fp8_f32(q0, q1, 0, false);
  ((unsigned short*)(xq + (size_t)row * HDIM + kb * 128))[lane] = (unsigned short)(pk & 0xFFFF);
  if (lane == 0) xsT[(size_t)kb * MDIM + row] = scale;
}

// ---------------------------------------------------------------------------
// Kernel 2: fused gate/up blockwise-fp8 GEMM + silu*u + per-row-128 fake quant.
// BK=64 double-buffered 2-phase pipeline, global_load_lds staging.
// Running-rescale accumulation: acc *= s_prev/s_cur per K-block, MFMA
// accumulates DIRECTLY into acc (no per-block blk[2][8] -> no VGPR spill;
// spill scratch was 10.2 GB of HBM writes = the R1/R2 bottleneck).
// ---------------------------------------------------------------------------
__global__ __launch_bounds__(256, 2)
void dual_gemm_silu_fq(const u8* __restrict__ xq, const float* __restrict__ xsT,
                       const u8* __restrict__ gw_cv, const u8* __restrict__ gw_raw,
                       const float* __restrict__ gs,
                       const u8* __restrict__ uw_cv, const u8* __restrict__ uw_raw,
                       const float* __restrict__ us,
                       u8* __restrict__ hq, float* __restrict__ hsT,
                       const int* __restrict__ flag_p, const int use_conv) {
  // [A|G|U] x [buf0|buf1] x 8 KB; first 16 KB reused as output byte tile.
  __shared__ __align__(16) u8 lds[49152];

  const int tid = threadIdx.x;
  const int lane = tid & 63, wid = tid >> 6;
  const int quad = lane >> 4, l16 = lane & 15;

  // XCD-chunked swizzle: 3584 = 8 * 448 (bijective).
  const int bid0 = blockIdx.x;
  const int bid = (bid0 & 7) * 448 + (bid0 >> 3);
  const int mi = bid & 31, ni = bid >> 5;
  const size_t m0 = (size_t)mi << 7, n0 = (size_t)ni << 7;

  const u8* gw = gw_raw;
  const u8* uw = uw_raw;
  if (use_conv) {
    if (*flag_p != 0) { gw = gw_cv; uw = uw_cv; }
  }

  const u8* baseA = xq + m0 * HDIM;
  const u8* baseG = gw + n0 * HDIM;
  const u8* baseU = uw + n0 * HDIM;

  const int r16 = lane >> 2, slot = lane & 3;
  u32 srcoff[2], dstoff[2];
#pragma unroll
  for (int i = 0; i < 2; ++i) {
    const int row = wid * 32 + i * 16 + r16;
    srcoff[i] = (u32)(row * HDIM) + (u32)((slot ^ swz4(row)) << 4);
    dstoff[i] = (u32)(wid * 2048 + i * 1024);
  }

  int offA[2], offB[8];
#pragma unroll
  for (int mt = 0; mt < 2; ++mt) offA[mt] = frag_off(wid * 32 + mt * 16 + l16, quad);
#pragma unroll
  for (int nt = 0; nt < 8; ++nt) offB[nt] = frag_off(nt * 16 + l16, quad);

  floatx4 accG[2][8], accU[2][8];
#pragma unroll
  for (int mt = 0; mt < 2; ++mt)
#pragma unroll
    for (int nt = 0; nt < 8; ++nt) {
      accG[mt][nt] = {0.f, 0.f, 0.f, 0.f};
      accU[mt][nt] = {0.f, 0.f, 0.f, 0.f};
    }

  auto STAGE = [&](int t, int b) {
    const u32 ko = (u32)t << 6;
    const u32 bo = (u32)b << 13;
#pragma unroll
    for (int i = 0; i < 2; ++i) {
      gload16(baseA + srcoff[i] + ko, &lds[bo + dstoff[i]]);
      gload16(baseG + srcoff[i] + ko, &lds[16384u + bo + dstoff[i]]);
      gload16(baseU + srcoff[i] + ko, &lds[32768u + bo + dstoff[i]]);
    }
  };

  // HALF: MFMAs straight into accG/accU (pre-scaled to current K-block units)
  auto HALF = [&](int b) {
    const u8* bufA = lds + (b << 13);
    const u8* bufG = lds + 16384 + (b << 13);
    const u8* bufU = lds + 32768 + (b << 13);
    longx2 aF[2];
#pragma unroll
    for (int mt = 0; mt < 2; ++mt) aF[mt] = *(const longx2*)(bufA + offA[mt]);

    __builtin_amdgcn_s_setprio(1);
#pragma unroll
    for (int nt = 0; nt < 8; ++nt) {
      const longx2 bF = *(const longx2*)(bufG + offB[nt]);
#pragma unroll
      for (int mt = 0; mt < 2; ++mt) {
        accG[mt][nt] = __builtin_amdgcn_mfma_f32_16x16x32_fp8_fp8(aF[mt][0], bF[0], accG[mt][nt], 0, 0, 0);
        accG[mt][nt] = __builtin_amdgcn_mfma_f32_16x16x32_fp8_fp8(aF[mt][1], bF[1], accG[mt][nt], 0, 0, 0);
      }
    }
#pragma unroll
    for (int nt = 0; nt < 8; ++nt) {
      const longx2 bF = *(const longx2*)(bufU + offB[nt]);
#pragma unroll
      for (int mt = 0; mt < 2; ++mt) {
        accU[mt][nt] = __builtin_amdgcn_mfma_f32_16x16x32_fp8_fp8(aF[mt][0], bF[0], accU[mt][nt], 0, 0, 0);
        accU[mt][nt] = __builtin_amdgcn_mfma_f32_16x16x32_fp8_fp8(aF[mt][1], bF[1], accU[mt][nt], 0, 0, 0);
      }
    }
    __builtin_amdgcn_s_setprio(0);
  };

  STAGE(0, 0);
  asm volatile("s_waitcnt vmcnt(0)" ::: "memory");
  __builtin_amdgcn_s_barrier();

  float prG[2][4], prU[2][4];  // effective scale the acc currently carries

  for (int kb = 0; kb < 32; ++kb) {
    const float sg = gs[ni * 32 + kb];
    const float su = us[ni * 32 + kb];
    float cG[2][4], cU[2][4];
#pragma unroll
    for (int mt = 0; mt < 2; ++mt) {
      const float4 v = *(const float4*)(xsT + (size_t)kb * MDIM + m0 + wid * 32 + mt * 16 + quad * 4);
      cG[mt][0] = v.x * sg; cG[mt][1] = v.y * sg; cG[mt][2] = v.z * sg; cG[mt][3] = v.w * sg;
      cU[mt][0] = v.x * su; cU[mt][1] = v.y * su; cU[mt][2] = v.z * su; cU[mt][3] = v.w * su;
    }
    if (kb) {
      float rG[2][4], rU[2][4];
#pragma unroll
      for (int mt = 0; mt < 2; ++mt)
#pragma unroll
        for (int r = 0; r < 4; ++r) {
          rG[mt][r] = prG[mt][r] / cG[mt][r];
          rU[mt][r] = prU[mt][r] / cU[mt][r];
        }
#pragma unroll
      for (int mt = 0; mt < 2; ++mt)
#pragma unroll
        for (int nt = 0; nt < 8; ++nt)
#pragma unroll
          for (int r = 0; r < 4; ++r) {
            accG[mt][nt][r] *= rG[mt][r];
            accU[mt][nt][r] *= rU[mt][r];
          }
    }
#pragma unroll
    for (int mt = 0; mt < 2; ++mt)
#pragma unroll
      for (int r = 0; r < 4; ++r) { prG[mt][r] = cG[mt][r]; prU[mt][r] = cU[mt][r]; }

    STAGE(2 * kb + 1, 1);          // prefetch odd half under even-half compute
    HALF(0);
    asm volatile("s_waitcnt vmcnt(0)" ::: "memory");
    __builtin_amdgcn_s_barrier();
    if (kb + 1 < 32) STAGE(2 * kb + 2, 0);
    HALF(1);
    asm volatile("s_waitcnt vmcnt(0)" ::: "memory");
    __builtin_amdgcn_s_barrier();
  }

  // undo running-scale: multiply by last block's effective scale
#pragma unroll
  for (int mt = 0; mt < 2; ++mt)
#pragma unroll
    for (int nt = 0; nt < 8; ++nt)
#pragma unroll
      for (int r = 0; r < 4; ++r) {
        accG[mt][nt][r] *= prG[mt][r];
        accU[mt][nt][r] *= prU[mt][r];
      }

  // ---- epilogue: h = silu(g)*u, per-row fake quant over this 128-col group.
  // Stage bytes into LDS (row-major [128][128]) then store coalesced.
  u8* ot = lds;  // 16 KB, safe: all waves past final barrier
#pragma unroll
  for (int mt = 0; mt < 2; ++mt) {
    float h[8][4];
    float amax[4] = {0.f, 0.f, 0.f, 0.f};
#pragma unroll
    for (int nt = 0; nt < 8; ++nt)
#pragma unroll
      for (int r = 0; r < 4; ++r) {
        const float gv = accG[mt][nt][r];
        const float uv = accU[mt][nt][r];
        const float hv = (gv / (1.f + __expf(-gv))) * uv;
        h[nt][r] = hv;
        amax[r] = fmaxf(amax[r], fabsf(hv));
      }
#pragma unroll
    for (int off = 1; off < 16; off <<= 1)
#pragma unroll
      for (int r = 0; r < 4; ++r)
        amax[r] = fmaxf(amax[r], __shfl_xor(amax[r], off, 64));

    float scale[4];
#pragma unroll
    for (int r = 0; r < 4; ++r) scale[r] = fmaxf(amax[r] / FP8MAX, 1e-12f);

    const int rowl = wid * 32 + mt * 16 + quad * 4;
    if (l16 == 0) {
#pragma unroll
      for (int r = 0; r < 4; ++r)
        hsT[(size_t)ni * MDIM + m0 + rowl + r] = scale[r];
    }
#pragma unroll
    for (int nt = 0; nt < 8; ++nt)
#pragma unroll
      for (int r = 0; r < 4; ++r) {
        const float q = fminf(fmaxf(h[nt][r] / scale[r], -FP8MAX), FP8MAX);
        const int pk = __builtin_amdgcn_cvt_pk_fp8_f32(q, 0.f, 0, false);
        ot[(rowl + r) * 128 + nt * 16 + l16] = (u8)(pk & 0xFF);
      }
  }
  __syncthreads();
  {
    const int row = tid >> 1, half = tid & 1;
    const uint4* s = (const uint4*)(ot + row * 128 + half * 64);
    uint4* d = (uint4*)(hq + (m0 + row) * IDIM + n0 + half * 64);
#pragma unroll
    for (int i = 0; i < 4; ++i) d[i] = s[i];
  }
}

// ---------------------------------------------------------------------------
// Kernel 3: down projection. Same pipeline + running-rescale accumulation.
// ---------------------------------------------------------------------------
__global__ __launch_bounds__(256, 2)
void gemm_down(const u8* __restrict__ hq, const float* __restrict__ hsT,
               const u8* __restrict__ dw_cv, const u8* __restrict__ dw_raw,
               const float* __restrict__ dsc, float* __restrict__ out,
               const int* __restrict__ flag_p, const int use_conv) {
  __shared__ __align__(16) u8 lds[32768];  // [A|B] x [buf0|buf1] x 8 KB

  const int tid = threadIdx.x;
  const int lane = tid & 63, wid = tid >> 6;
  const int quad = lane >> 4, l16 = lane & 15;

  const int bid0 = blockIdx.x;
  const int bid = (bid0 & 7) * 128 + (bid0 >> 3);  // 1024 = 8 * 128
  const int mi = bid & 31, ni = bid >> 5;
  const size_t m0 = (size_t)mi << 7, n0 = (size_t)ni << 7;

  const u8* dw = dw_raw;
  if (use_conv) {
    if (*flag_p != 0) dw = dw_cv;
  }

  const u8* baseA = hq + m0 * IDIM;
  const u8* baseB = dw + n0 * IDIM;

  const int r16 = lane >> 2, slot = lane & 3;
  u32 srcoff[2], dstoff[2];
#pragma unroll
  for (int i = 0; i < 2; ++i) {
    const int row = wid * 32 + i * 16 + r16;
    srcoff[i] = (u32)(row * IDIM) + (u32)((slot ^ swz4(row)) << 4);
    dstoff[i] = (u32)(wid * 2048 + i * 1024);
  }

  int offA[2], offB[8];
#pragma unroll
  for (int mt = 0; mt < 2; ++mt) offA[mt] = frag_off(wid * 32 + mt * 16 + l16, quad);
#pragma unroll
  for (int nt = 0; nt < 8; ++nt) offB[nt] = frag_off(nt * 16 + l16, quad);

  floatx4 acc[2][8];
#pragma unroll
  for (int mt = 0; mt < 2; ++mt)
#pragma unroll
    for (int nt = 0; nt < 8; ++nt) acc[mt][nt] = {0.f, 0.f, 0.f, 0.f};

  auto STAGE = [&](int t, int b) {
    const u32 ko = (u32)t << 6;
    const u32 bo = (u32)b << 13;
#pragma unroll
    for (int i = 0; i < 2; ++i) {
      gload16(baseA + srcoff[i] + ko, &lds[bo + dstoff[i]]);
      gload16(baseB + srcoff[i] + ko, &lds[16384u + bo + dstoff[i]]);
    }
  };

  auto HALF = [&](int b) {
    const u8* bufA = lds + (b << 13);
    const u8* bufB = lds + 16384 + (b << 13);
    longx2 aF[2];
#pragma unroll
    for (int mt = 0; mt < 2; ++mt) aF[mt] = *(const longx2*)(bufA + offA[mt]);
    __builtin_amdgcn_s_setprio(1);
#pragma unroll
    for (int nt = 0; nt < 8; ++nt) {
      const longx2 bF = *(const longx2*)(bufB + offB[nt]);
#pragma unroll
      for (int mt = 0; mt < 2; ++mt) {
        acc[mt][nt] = __builtin_amdgcn_mfma_f32_16x16x32_fp8_fp8(aF[mt][0], bF[0], acc[mt][nt], 0, 0, 0);
        acc[mt][nt] = __builtin_amdgcn_mfma_f32_16x16x32_fp8_fp8(aF[mt][1], bF[1], acc[mt][nt], 0, 0, 0);
      }
    }
    __builtin_amdgcn_s_setprio(0);
  };

  STAGE(0, 0);
  asm volatile("s_waitcnt vmcnt(0)" ::: "memory");
  __builtin_amdgcn_s_barrier();

  float prS[2][4];
  for (int kb = 0; kb < 112; ++kb) {
    const float sd = dsc[ni * 112 + kb];
    float cS[2][4];
#pragma unroll
    for (int mt = 0; mt < 2; ++mt) {
      const float4 v = *(const float4*)(hsT + (size_t)kb * MDIM + m0 + wid * 32 + mt * 16 + quad * 4);
      cS[mt][0] = v.x * sd; cS[mt][1] = v.y * sd; cS[mt][2] = v.z * sd; cS[mt][3] = v.w * sd;
    }
    if (kb) {
      float rS[2][4];
#pragma unroll
      for (int mt = 0; mt < 2; ++mt)
#pragma unroll
        for (int r = 0; r < 4; ++r) rS[mt][r] = prS[mt][r] / cS[mt][r];
#pragma unroll
      for (int mt = 0; mt < 2; ++mt)
#pragma unroll
        for (int nt = 0; nt < 8; ++nt)
#pragma unroll
          for (int r = 0; r < 4; ++r) acc[mt][nt][r] *= rS[mt][r];
    }
#pragma unroll
    for (int mt = 0; mt < 2; ++mt)
#pragma unroll
      for (int r = 0; r < 4; ++r) prS[mt][r] = cS[mt][r];

    STAGE(2 * kb + 1, 1);
    HALF(0);
    asm volatile("s_waitcnt vmcnt(0)" ::: "memory");
    __builtin_amdgcn_s_barrier();
    if (kb + 1 < 112) STAGE(2 * kb + 2, 0);
    HALF(1);
    asm volatile("s_waitcnt vmcnt(0)" ::: "memory");
    __builtin_amdgcn_s_barrier();
  }

#pragma unroll
  for (int mt = 0; mt < 2; ++mt) {
    const int rowl = wid * 32 + mt * 16 + quad * 4;
#pragma unroll
    for (int nt = 0; nt < 8; ++nt)
#pragma unroll
      for (int r = 0; r < 4; ++r)
        out[(m0 + rowl + r) * (size_t)HDIM + n0 + nt * 16 + l16] = acc[mt][nt][r] * prS[mt][r];
  }
}

// ---------------------------------------------------------------------------
extern "C" void kernel_launch(void* const* d_in, const int* in_sizes, int n_in,
                              void* d_out, int out_size, void* d_ws, size_t ws_size,
                              hipStream_t stream) {
  const float* x   = (const float*)d_in[0];
  const void* gw_s = d_in[1];
  const float* gs  = (const float*)d_in[2];
  const void* uw_s = d_in[3];
  const float* us  = (const float*)d_in[4];
  const void* dw_s = d_in[5];
  const float* dsc = (const float*)d_in[6];
  float* out       = (float*)d_out;

  const size_t NW = (size_t)IDIM * HDIM;  // 58,720,256 elements per weight

  unsigned char* ws = (unsigned char*)d_ws;
  unsigned char* xq = ws;                         // 16 MB
  float* xsT = (float*)(ws + 16777216);           // 512 KB
  unsigned char* hq  = ws + 17301504;             // 56 MB
  float* hsT = (float*)(ws + 76021760);           // 1.75 MB
  unsigned char* gwq = ws + 77856768;             // 56 MB
  unsigned char* uwq = ws + 136577024;            // 56 MB
  unsigned char* dwq = gwq;                       // reuse gate slot after dual_gemm
  int* flag = (int*)(ws + 195297280);

  const bool fits = ws_size >= (size_t)195297284;
  const int use_conv = fits ? 1 : 0;

  const int convBlocks = (int)(NW / (16 * 256));  // 14336, exact

  if (fits) {
    detect_dtype<<<1, 64, 0, stream>>>((const unsigned int*)gw_s, flag);
    conv_w<<<convBlocks, 256, 0, stream>>>(gw_s, gwq, flag);
    conv_w<<<convBlocks, 256, 0, stream>>>(uw_s, uwq, flag);
  }
  fq_act<<<(MDIM * (HDIM / 128)) / 4, 256, 0, stream>>>(x, xq, xsT);
  dual_gemm_silu_fq<<<(MDIM / 128) * (IDIM / 128), 256, 0, stream>>>(
      xq, xsT, gwq, (const unsigned char*)gw_s, gs,
      uwq, (const unsigned char*)uw_s, us, hq, hsT, flag, use_conv);
  if (fits) {
    conv_w<<<convBlocks, 256, 0, stream>>>(dw_s, dwq, flag);
  }
  gemm_down<<<(MDIM / 128) * (HDIM / 128), 256, 0, stream>>>(
      hq, hsT, dwq, (const unsigned char*)dw_s, dsc, out, flag, use_conv);
}

// Round 4
// 1886.315 us; speedup vs baseline: 2.8873x; 1.0512x over previous
//
#include <hip/hip_runtime.h>

typedef float floatx4 __attribute__((ext_vector_type(4)));
typedef long longx2 __attribute__((ext_vector_type(2)));
typedef unsigned int u32;
typedef unsigned char u8;

#define MDIM 4096
#define HDIM 4096
#define IDIM 14336
#define FP8MAX 448.0f

// ---------------------------------------------------------------------------
// LDS tile geometry (BK=64): 128 rows x 64 B per buffer (8 KB).
// 16B chunk c of row r lives at slot (c ^ swz4(r)), swz4(r) = (r^(r>>2))&3.
// global_load_lds writes LINEARLY (uniform base + lane*16), so we pre-swizzle
// the per-lane GLOBAL source address instead (both-sides-or-neither rule).
// ---------------------------------------------------------------------------
__device__ __forceinline__ int swz4(int r) { return (r ^ (r >> 2)) & 3; }
__device__ __forceinline__ int frag_off(int row, int quad) {
  return (row << 6) + ((quad ^ swz4(row)) << 4);
}

__device__ __forceinline__ void gload16(const u8* g, u8* l) {
  __builtin_amdgcn_global_load_lds((const __attribute__((address_space(1))) u32*)g,
                                   (__attribute__((address_space(3))) u32*)l, 16, 0, 0);
}

// ---------------------------------------------------------------------------
// Weight-dtype detection: 2 = fp32, 1 = bf16, 0 = raw fp8 bytes.
// ---------------------------------------------------------------------------
__global__ void detect_dtype(const unsigned int* __restrict__ w, int* __restrict__ flag) {
  if (threadIdx.x == 0 && blockIdx.x == 0) {
    bool f32 = true, b16 = true;
    for (int i = 0; i < 64; ++i) {
      const unsigned int v = w[i];
      if (v & 0xFFFFFu) f32 = false;
      if ((v & 0xFu) || ((v >> 16) & 0xFu)) b16 = false;
    }
    *flag = f32 ? 2 : (b16 ? 1 : 0);
  }
}

__device__ __forceinline__ float bfu(unsigned int bits16) {
  union { unsigned int u; float f; } c;
  c.u = bits16 << 16;
  return c.f;
}

__device__ __forceinline__ unsigned int pack2(unsigned int lo, unsigned int hi) {
  int pk = __builtin_amdgcn_cvt_pk_fp8_f32(bfu(lo & 0xFFFFu), bfu(lo >> 16), 0, false);
  pk = __builtin_amdgcn_cvt_pk_fp8_f32(bfu(hi & 0xFFFFu), bfu(hi >> 16), pk, true);
  return (unsigned int)pk;
}

// Convert one weight matrix to fp8 bytes. flag==0 (already fp8): no-op, the
// GEMMs read the raw input buffer directly.
__global__ __launch_bounds__(256) void conv_w(const void* __restrict__ src,
                                              unsigned char* __restrict__ dst,
                                              const int* __restrict__ flag_p) {
  const int flag = *flag_p;
  if (flag == 0) return;
  const long t = (long)blockIdx.x * 256 + threadIdx.x;  // 16 elements per thread
  uint4 out;
  if (flag == 2) {
    const float4* s = (const float4*)src;
    unsigned int o[4];
#pragma unroll
    for (int p = 0; p < 4; ++p) {
      const float4 v = s[t * 4 + p];
      int pk = __builtin_amdgcn_cvt_pk_fp8_f32(v.x, v.y, 0, false);
      pk = __builtin_amdgcn_cvt_pk_fp8_f32(v.z, v.w, pk, true);
      o[p] = (unsigned int)pk;
    }
    out = make_uint4(o[0], o[1], o[2], o[3]);
  } else {
    const uint4* s = (const uint4*)src;
    const uint4 a = s[t * 2], b = s[t * 2 + 1];
    out = make_uint4(pack2(a.x, a.y), pack2(a.z, a.w),
                     pack2(b.x, b.y), pack2(b.z, b.w));
  }
  ((uint4*)dst)[t] = out;
}

// ---------------------------------------------------------------------------
// Kernel 1: fake-quant activations. One wave per (row, 128-col group).
// ---------------------------------------------------------------------------
__global__ __launch_bounds__(256) void fq_act(const float* __restrict__ x,
                                              unsigned char* __restrict__ xq,
                                              float* __restrict__ xsT) {
  const int tid = threadIdx.x;
  const int lane = tid & 63, w = tid >> 6;
  const int g = blockIdx.x * 4 + w;
  const int row = g >> 5, kb = g & 31;

  const float2 v = ((const float2*)(x + (size_t)row * HDIM + kb * 128))[lane];
  float amax = fmaxf(fabsf(v.x), fabsf(v.y));
#pragma unroll
  for (int off = 1; off < 64; off <<= 1)
    amax = fmaxf(amax, __shfl_xor(amax, off, 64));

  const float scale = fmaxf(amax / FP8MAX, 1e-12f);
  const float q0 = fminf(fmaxf(v.x / scale, -FP8MAX), FP8MAX);
  const float q1 = fminf(fmaxf(v.y / scale, -FP8MAX), FP8MAX);
  const int pk = __builtin_amdgcn_cvt_pk_fp8_f32(q0, q1, 0, false);
  ((unsigned short*)(xq + (size_t)row * HDIM + kb * 128))[lane] = (unsigned short)(pk & 0xFFFF);
  if (lane == 0) xsT[(size_t)kb * MDIM + row] = scale;
}

// ---------------------------------------------------------------------------
// Kernel 2: fused gate/up blockwise-fp8 GEMM + silu*u + per-row-128 fake quant.
// 3-buffer LDS ring, counted vmcnt (never drains to 0 mid-loop): STAGE for
// half t+2 issued a full phase before its consumer wait -> DMA gets ~2 phases
// of slack. Scales prefetched one kb ahead into regs. Running-rescale acc.
// ---------------------------------------------------------------------------
__global__ __launch_bounds__(256, 2)
void dual_gemm_silu_fq(const u8* __restrict__ xq, const float* __restrict__ xsT,
                       const u8* __restrict__ gw_cv, const u8* __restrict__ gw_raw,
                       const float* __restrict__ gs,
                       const u8* __restrict__ uw_cv, const u8* __restrict__ uw_raw,
                       const float* __restrict__ us,
                       u8* __restrict__ hq, float* __restrict__ hsT,
                       const int* __restrict__ flag_p, const int use_conv) {
  // 3 ring buffers x (A 8K | G 8K | U 8K); first 16 KB reused for output tile.
  __shared__ __align__(16) u8 lds[73728];

  const int tid = threadIdx.x;
  const int lane = tid & 63, wid = tid >> 6;
  const int quad = lane >> 4, l16 = lane & 15;

  // XCD-chunked swizzle: 3584 = 8 * 448 (bijective).
  const int bid0 = blockIdx.x;
  const int bid = (bid0 & 7) * 448 + (bid0 >> 3);
  const int mi = bid & 31, ni = bid >> 5;
  const size_t m0 = (size_t)mi << 7, n0 = (size_t)ni << 7;

  const u8* gw = gw_raw;
  const u8* uw = uw_raw;
  if (use_conv) {
    if (*flag_p != 0) { gw = gw_cv; uw = uw_cv; }
  }

  const u8* baseA = xq + m0 * HDIM;
  const u8* baseG = gw + n0 * HDIM;
  const u8* baseU = uw + n0 * HDIM;

  const int r16 = lane >> 2, slot = lane & 3;
  u32 srcoff[2], dstoff[2];
#pragma unroll
  for (int i = 0; i < 2; ++i) {
    const int row = wid * 32 + i * 16 + r16;
    srcoff[i] = (u32)(row * HDIM) + (u32)((slot ^ swz4(row)) << 4);
    dstoff[i] = (u32)(wid * 2048 + i * 1024);
  }

  int offA[2], offB[8];
#pragma unroll
  for (int mt = 0; mt < 2; ++mt) offA[mt] = frag_off(wid * 32 + mt * 16 + l16, quad);
#pragma unroll
  for (int nt = 0; nt < 8; ++nt) offB[nt] = frag_off(nt * 16 + l16, quad);

  floatx4 accG[2][8], accU[2][8];
#pragma unroll
  for (int mt = 0; mt < 2; ++mt)
#pragma unroll
    for (int nt = 0; nt < 8; ++nt) {
      accG[mt][nt] = {0.f, 0.f, 0.f, 0.f};
      accU[mt][nt] = {0.f, 0.f, 0.f, 0.f};
    }

  auto STAGE = [&](int t, int b) {
    const u32 ko = (u32)t << 6;
    u8* lb = lds + b * 24576;
#pragma unroll
    for (int i = 0; i < 2; ++i) {
      gload16(baseA + srcoff[i] + ko, lb + dstoff[i]);
      gload16(baseG + srcoff[i] + ko, lb + 8192u + dstoff[i]);
      gload16(baseU + srcoff[i] + ko, lb + 16384u + dstoff[i]);
    }
  };

  auto HALF = [&](int b) {
    const u8* lb = lds + b * 24576;
    const u8* bufA = lb;
    const u8* bufG = lb + 8192;
    const u8* bufU = lb + 16384;
    longx2 aF[2];
#pragma unroll
    for (int mt = 0; mt < 2; ++mt) aF[mt] = *(const longx2*)(bufA + offA[mt]);

    __builtin_amdgcn_s_setprio(1);
#pragma unroll
    for (int nt = 0; nt < 8; ++nt) {
      const longx2 bF = *(const longx2*)(bufG + offB[nt]);
#pragma unroll
      for (int mt = 0; mt < 2; ++mt) {
        accG[mt][nt] = __builtin_amdgcn_mfma_f32_16x16x32_fp8_fp8(aF[mt][0], bF[0], accG[mt][nt], 0, 0, 0);
        accG[mt][nt] = __builtin_amdgcn_mfma_f32_16x16x32_fp8_fp8(aF[mt][1], bF[1], accG[mt][nt], 0, 0, 0);
      }
    }
#pragma unroll
    for (int nt = 0; nt < 8; ++nt) {
      const longx2 bF = *(const longx2*)(bufU + offB[nt]);
#pragma unroll
      for (int mt = 0; mt < 2; ++mt) {
        accU[mt][nt] = __builtin_amdgcn_mfma_f32_16x16x32_fp8_fp8(aF[mt][0], bF[0], accU[mt][nt], 0, 0, 0);
        accU[mt][nt] = __builtin_amdgcn_mfma_f32_16x16x32_fp8_fp8(aF[mt][1], bF[1], accU[mt][nt], 0, 0, 0);
      }
    }
    __builtin_amdgcn_s_setprio(0);
  };

  // scale prefetch for kb=0 (issued BEFORE the staging DMAs)
  const float* xrow = xsT + m0 + wid * 32 + quad * 4;
  float4 xv0 = *(const float4*)(xrow);
  float4 xv1 = *(const float4*)(xrow + 16);
  float sgn = gs[ni * 32];
  float sun = us[ni * 32];

  STAGE(0, 0);
  STAGE(1, 1);

  float prX[2][4];
  float sgp = 1.f, sup = 1.f;
  int cb = 0;

  for (int kb = 0; kb < 32; ++kb) {
    float cx[2][4];
    cx[0][0] = xv0.x; cx[0][1] = xv0.y; cx[0][2] = xv0.z; cx[0][3] = xv0.w;
    cx[1][0] = xv1.x; cx[1][1] = xv1.y; cx[1][2] = xv1.z; cx[1][3] = xv1.w;
    const float sgc = sgn, suc = sun;
    if (kb) {
      const float rgs = sgp / sgc, rus = sup / suc;
#pragma unroll
      for (int mt = 0; mt < 2; ++mt)
#pragma unroll
        for (int r = 0; r < 4; ++r) {
          const float cm = prX[mt][r] / cx[mt][r];
          const float rg = cm * rgs, ru = cm * rus;
#pragma unroll
          for (int nt = 0; nt < 8; ++nt) {
            accG[mt][nt][r] *= rg;
            accU[mt][nt][r] *= ru;
          }
        }
    }
#pragma unroll
    for (int mt = 0; mt < 2; ++mt)
#pragma unroll
      for (int r = 0; r < 4; ++r) prX[mt][r] = cx[mt][r];
    sgp = sgc; sup = suc;

    if (kb + 1 < 32) {  // prefetch next kb's scales (one kb of slack)
      const float* xn = xsT + (size_t)(kb + 1) * MDIM + m0 + wid * 32 + quad * 4;
      xv0 = *(const float4*)(xn);
      xv1 = *(const float4*)(xn + 16);
      sgn = gs[ni * 32 + kb + 1];
      sun = us[ni * 32 + kb + 1];
    }

    // ---- half 1 (t = 2kb) ----
    {
      int sb = cb + 2; if (sb >= 3) sb -= 3;
      if (kb < 31) {
        STAGE(2 * kb + 2, sb);
        asm volatile("s_waitcnt vmcnt(12)" ::: "memory");
      } else {
        asm volatile("s_waitcnt vmcnt(6)" ::: "memory");
      }
      __builtin_amdgcn_s_barrier();
      HALF(cb);
      __builtin_amdgcn_s_barrier();
      cb = cb + 1; if (cb >= 3) cb -= 3;
    }
    // ---- half 2 (t = 2kb+1) ----
    {
      int sb = cb + 2; if (sb >= 3) sb -= 3;
      if (kb < 31) {
        STAGE(2 * kb + 3, sb);
        asm volatile("s_waitcnt vmcnt(12)" ::: "memory");
      } else {
        asm volatile("s_waitcnt vmcnt(0)" ::: "memory");
      }
      __builtin_amdgcn_s_barrier();
      HALF(cb);
      __builtin_amdgcn_s_barrier();
      cb = cb + 1; if (cb >= 3) cb -= 3;
    }
  }

  // undo running-scale
#pragma unroll
  for (int mt = 0; mt < 2; ++mt)
#pragma unroll
    for (int r = 0; r < 4; ++r) {
      const float fg = prX[mt][r] * sgp;
      const float fu = prX[mt][r] * sup;
#pragma unroll
      for (int nt = 0; nt < 8; ++nt) {
        accG[mt][nt][r] *= fg;
        accU[mt][nt][r] *= fu;
      }
    }

  // ---- epilogue: h = silu(g)*u, per-row fake quant over this 128-col group.
  // Stage bytes into LDS (row-major [128][128]) then store coalesced.
  u8* ot = lds;  // 16 KB, safe: all waves past final barrier
#pragma unroll
  for (int mt = 0; mt < 2; ++mt) {
    float h[8][4];
    float amax[4] = {0.f, 0.f, 0.f, 0.f};
#pragma unroll
    for (int nt = 0; nt < 8; ++nt)
#pragma unroll
      for (int r = 0; r < 4; ++r) {
        const float gv = accG[mt][nt][r];
        const float uv = accU[mt][nt][r];
        const float hv = (gv / (1.f + __expf(-gv))) * uv;
        h[nt][r] = hv;
        amax[r] = fmaxf(amax[r], fabsf(hv));
      }
#pragma unroll
    for (int off = 1; off < 16; off <<= 1)
#pragma unroll
      for (int r = 0; r < 4; ++r)
        amax[r] = fmaxf(amax[r], __shfl_xor(amax[r], off, 64));

    float scale[4];
#pragma unroll
    for (int r = 0; r < 4; ++r) scale[r] = fmaxf(amax[r] / FP8MAX, 1e-12f);

    const int rowl = wid * 32 + mt * 16 + quad * 4;
    if (l16 == 0) {
#pragma unroll
      for (int r = 0; r < 4; ++r)
        hsT[(size_t)ni * MDIM + m0 + rowl + r] = scale[r];
    }
#pragma unroll
    for (int nt = 0; nt < 8; ++nt)
#pragma unroll
      for (int r = 0; r < 4; ++r) {
        const float q = fminf(fmaxf(h[nt][r] / scale[r], -FP8MAX), FP8MAX);
        const int pk = __builtin_amdgcn_cvt_pk_fp8_f32(q, 0.f, 0, false);
        ot[(rowl + r) * 128 + nt * 16 + l16] = (u8)(pk & 0xFF);
      }
  }
  __syncthreads();
  {
    const int row = tid >> 1, half = tid & 1;
    const uint4* s = (const uint4*)(ot + row * 128 + half * 64);
    uint4* d = (uint4*)(hq + (m0 + row) * IDIM + n0 + half * 64);
#pragma unroll
    for (int i = 0; i < 4; ++i) d[i] = s[i];
  }
}

// ---------------------------------------------------------------------------
// Kernel 3: down projection. Same 3-buffer ring + counted vmcnt + prefetch.
// ---------------------------------------------------------------------------
__global__ __launch_bounds__(256, 2)
void gemm_down(const u8* __restrict__ hq, const float* __restrict__ hsT,
               const u8* __restrict__ dw_cv, const u8* __restrict__ dw_raw,
               const float* __restrict__ dsc, float* __restrict__ out,
               const int* __restrict__ flag_p, const int use_conv) {
  __shared__ __align__(16) u8 lds[49152];  // 3 ring bufs x (A 8K | B 8K)

  const int tid = threadIdx.x;
  const int lane = tid & 63, wid = tid >> 6;
  const int quad = lane >> 4, l16 = lane & 15;

  const int bid0 = blockIdx.x;
  const int bid = (bid0 & 7) * 128 + (bid0 >> 3);  // 1024 = 8 * 128
  const int mi = bid & 31, ni = bid >> 5;
  const size_t m0 = (size_t)mi << 7, n0 = (size_t)ni << 7;

  const u8* dw = dw_raw;
  if (use_conv) {
    if (*flag_p != 0) dw = dw_cv;
  }

  const u8* baseA = hq + m0 * IDIM;
  const u8* baseB = dw + n0 * IDIM;

  const int r16 = lane >> 2, slot = lane & 3;
  u32 srcoff[2], dstoff[2];
#pragma unroll
  for (int i = 0; i < 2; ++i) {
    const int row = wid * 32 + i * 16 + r16;
    srcoff[i] = (u32)(row * IDIM) + (u32)((slot ^ swz4(row)) << 4);
    dstoff[i] = (u32)(wid * 2048 + i * 1024);
  }

  int offA[2], offB[8];
#pragma unroll
  for (int mt = 0; mt < 2; ++mt) offA[mt] = frag_off(wid * 32 + mt * 16 + l16, quad);
#pragma unroll
  for (int nt = 0; nt < 8; ++nt) offB[nt] = frag_off(nt * 16 + l16, quad);

  floatx4 acc[2][8];
#pragma unroll
  for (int mt = 0; mt < 2; ++mt)
#pragma unroll
    for (int nt = 0; nt < 8; ++nt) acc[mt][nt] = {0.f, 0.f, 0.f, 0.f};

  auto STAGE = [&](int t, int b) {
    const u32 ko = (u32)t << 6;
    u8* lb = lds + b * 16384;
#pragma unroll
    for (int i = 0; i < 2; ++i) {
      gload16(baseA + srcoff[i] + ko, lb + dstoff[i]);
      gload16(baseB + srcoff[i] + ko, lb + 8192u + dstoff[i]);
    }
  };

  auto HALF = [&](int b) {
    const u8* lb = lds + b * 16384;
    longx2 aF[2];
#pragma unroll
    for (int mt = 0; mt < 2; ++mt) aF[mt] = *(const longx2*)(lb + offA[mt]);
    __builtin_amdgcn_s_setprio(1);
#pragma unroll
    for (int nt = 0; nt < 8; ++nt) {
      const longx2 bF = *(const longx2*)(lb + 8192 + offB[nt]);
#pragma unroll
      for (int mt = 0; mt < 2; ++mt) {
        acc[mt][nt] = __builtin_amdgcn_mfma_f32_16x16x32_fp8_fp8(aF[mt][0], bF[0], acc[mt][nt], 0, 0, 0);
        acc[mt][nt] = __builtin_amdgcn_mfma_f32_16x16x32_fp8_fp8(aF[mt][1], bF[1], acc[mt][nt], 0, 0, 0);
      }
    }
    __builtin_amdgcn_s_setprio(0);
  };

  // scale prefetch for kb=0
  const float* hrow = hsT + m0 + wid * 32 + quad * 4;
  float4 xv0 = *(const float4*)(hrow);
  float4 xv1 = *(const float4*)(hrow + 16);
  float sdn = dsc[ni * 112];

  STAGE(0, 0);
  STAGE(1, 1);

  float prX[2][4];
  float sdp = 1.f;
  int cb = 0;

  for (int kb = 0; kb < 112; ++kb) {
    float cx[2][4];
    cx[0][0] = xv0.x; cx[0][1] = xv0.y; cx[0][2] = xv0.z; cx[0][3] = xv0.w;
    cx[1][0] = xv1.x; cx[1][1] = xv1.y; cx[1][2] = xv1.z; cx[1][3] = xv1.w;
    const float sdc = sdn;
    if (kb) {
      const float rds = sdp / sdc;
#pragma unroll
      for (int mt = 0; mt < 2; ++mt)
#pragma unroll
        for (int r = 0; r < 4; ++r) {
          const float rr = (prX[mt][r] / cx[mt][r]) * rds;
#pragma unroll
          for (int nt = 0; nt < 8; ++nt) acc[mt][nt][r] *= rr;
        }
    }
#pragma unroll
    for (int mt = 0; mt < 2; ++mt)
#pragma unroll
      for (int r = 0; r < 4; ++r) prX[mt][r] = cx[mt][r];
    sdp = sdc;

    if (kb + 1 < 112) {
      const float* xn = hsT + (size_t)(kb + 1) * MDIM + m0 + wid * 32 + quad * 4;
      xv0 = *(const float4*)(xn);
      xv1 = *(const float4*)(xn + 16);
      sdn = dsc[ni * 112 + kb + 1];
    }

    // ---- half 1 ----
    {
      int sb = cb + 2; if (sb >= 3) sb -= 3;
      if (kb < 111) {
        STAGE(2 * kb + 2, sb);
        asm volatile("s_waitcnt vmcnt(8)" ::: "memory");
      } else {
        asm volatile("s_waitcnt vmcnt(4)" ::: "memory");
      }
      __builtin_amdgcn_s_barrier();
      HALF(cb);
      __builtin_amdgcn_s_barrier();
      cb = cb + 1; if (cb >= 3) cb -= 3;
    }
    // ---- half 2 ----
    {
      int sb = cb + 2; if (sb >= 3) sb -= 3;
      if (kb < 111) {
        STAGE(2 * kb + 3, sb);
        asm volatile("s_waitcnt vmcnt(8)" ::: "memory");
      } else {
        asm volatile("s_waitcnt vmcnt(0)" ::: "memory");
      }
      __builtin_amdgcn_s_barrier();
      HALF(cb);
      __builtin_amdgcn_s_barrier();
      cb = cb + 1; if (cb >= 3) cb -= 3;
    }
  }

#pragma unroll
  for (int mt = 0; mt < 2; ++mt) {
    const int rowl = wid * 32 + mt * 16 + quad * 4;
#pragma unroll
    for (int nt = 0; nt < 8; ++nt)
#pragma unroll
      for (int r = 0; r < 4; ++r)
        out[(m0 + rowl + r) * (size_t)HDIM + n0 + nt * 16 + l16] =
            acc[mt][nt][r] * prX[mt][r] * sdp;
  }
}

// ---------------------------------------------------------------------------
extern "C" void kernel_launch(void* const* d_in, const int* in_sizes, int n_in,
                              void* d_out, int out_size, void* d_ws, size_t ws_size,
                              hipStream_t stream) {
  const float* x   = (const float*)d_in[0];
  const void* gw_s = d_in[1];
  const float* gs  = (const float*)d_in[2];
  const void* uw_s = d_in[3];
  const float* us  = (const float*)d_in[4];
  const void* dw_s = d_in[5];
  const float* dsc = (const float*)d_in[6];
  float* out       = (float*)d_out;

  const size_t NW = (size_t)IDIM * HDIM;  // 58,720,256 elements per weight

  unsigned char* ws = (unsigned char*)d_ws;
  unsigned char* xq = ws;                         // 16 MB
  float* xsT = (float*)(ws + 16777216);           // 512 KB
  unsigned char* hq  = ws + 17301504;             // 56 MB
  float* hsT = (float*)(ws + 76021760);           // 1.75 MB
  unsigned char* gwq = ws + 77856768;             // 56 MB
  unsigned char* uwq = ws + 136577024;            // 56 MB
  unsigned char* dwq = gwq;                       // reuse gate slot after dual_gemm
  int* flag = (int*)(ws + 195297280);

  const bool fits = ws_size >= (size_t)195297284;
  const int use_conv = fits ? 1 : 0;

  const int convBlocks = (int)(NW / (16 * 256));  // 14336, exact

  if (fits) {
    detect_dtype<<<1, 64, 0, stream>>>((const unsigned int*)gw_s, flag);
    conv_w<<<convBlocks, 256, 0, stream>>>(gw_s, gwq, flag);
    conv_w<<<convBlocks, 256, 0, stream>>>(uw_s, uwq, flag);
  }
  fq_act<<<(MDIM * (HDIM / 128)) / 4, 256, 0, stream>>>(x, xq, xsT);
  dual_gemm_silu_fq<<<(MDIM / 128) * (IDIM / 128), 256, 0, stream>>>(
      xq, xsT, gwq, (const unsigned char*)gw_s, gs,
      uwq, (const unsigned char*)uw_s, us, hq, hsT, flag, use_conv);
  if (fits) {
    conv_w<<<convBlocks, 256, 0, stream>>>(dw_s, dwq, flag);
  }
  gemm_down<<<(MDIM / 128) * (HDIM / 128), 256, 0, stream>>>(
      hq, hsT, dwq, (const unsigned char*)dw_s, dsc, out, flag, use_conv);
}